// Round 1
// baseline (2232.690 us; speedup 1.0000x reference)
//
#include <hip/hip_runtime.h>

#define NTOT 8192
#define CDIM 512
#define KCL 27

static __device__ __forceinline__ unsigned short f2bf(float v) {
  union { float f; unsigned u; } z; z.f = v;
  unsigned r = (z.u + 0x7FFFu + ((z.u >> 16) & 1u)) >> 16;
  return (unsigned short)r;
}

// ---------------- K1: normalize clusters (27 x 512) ----------------
__global__ void k_norm_clusters(const float* __restrict__ cl, float* __restrict__ ncl) {
  int k = blockIdx.x;
  int t = threadIdx.x; // 64
  const float* row = cl + (size_t)k * CDIM;
  float ss = 0.f;
  for (int c = t; c < CDIM; c += 64) { float v = row[c]; ss += v * v; }
  for (int o = 32; o; o >>= 1) ss += __shfl_down(ss, o);
  ss = __shfl(ss, 0);
  float inv = 1.f / fmaxf(sqrtf(ss), 1e-12f);
  for (int c = t; c < CDIM; c += 64) ncl[(size_t)k * CDIM + c] = row[c] * inv;
}

// ---------------- K2: per-pixel L2 norm + permute(0,3,2,1) -> merged[N][C] ----------------
__global__ __launch_bounds__(256) void k_merged(const float* __restrict__ x, float* __restrict__ merged) {
  __shared__ float inv[64];
  __shared__ float part[4][64];
  __shared__ float tile[64][65];
  int bh = blockIdx.x;           // b*64 + h
  int b = bh >> 6, h = bh & 63;
  int t = threadIdx.x;
  int w = t & 63, cg = t >> 6;
  const float* xb = x + (size_t)b * CDIM * 4096 + (size_t)h * 64; // xb[c*4096 + w]
  float ss = 0.f;
  for (int c = cg; c < CDIM; c += 4) {
    float v = xb[(size_t)c * 4096 + w];
    ss += v * v;
  }
  part[cg][w] = ss;
  __syncthreads();
  if (t < 64) {
    float s2 = part[0][t] + part[1][t] + part[2][t] + part[3][t];
    inv[t] = 1.f / fmaxf(sqrtf(s2), 1e-12f);
  }
  __syncthreads();
  for (int c0 = 0; c0 < CDIM; c0 += 64) {
#pragma unroll
    for (int q = 0; q < 16; ++q) {
      int c = cg + q * 4;
      tile[c][w] = xb[(size_t)(c0 + c) * 4096 + w];
    }
    __syncthreads();
#pragma unroll
    for (int q = 0; q < 16; ++q) {
      int ww = cg + q * 4;
      int n = b * 4096 + ww * 64 + h;          // n from permute(0,3,2,1)
      merged[(size_t)n * CDIM + c0 + w] = tile[w][ww] * inv[ww];
    }
    __syncthreads();
  }
}

// ---------------- K3: inner vs clusters, softmax, log_softmax out, max, s, sT ----------------
__global__ __launch_bounds__(256) void k_inner(const float* __restrict__ merged,
    const float* __restrict__ ncl, const float* __restrict__ alpha_p,
    float* __restrict__ s, float* __restrict__ sT, float* __restrict__ maxv,
    float* __restrict__ out_cp) {
  __shared__ float ncll[KCL * 513];
  __shared__ float row[CDIM];
  __shared__ float partial[32][8];
  __shared__ float innerl[KCL];
  __shared__ float exps[KCL];
  int t = threadIdx.x;
  float alpha = alpha_p[0];
  for (int idx = t; idx < KCL * CDIM; idx += 256) {
    int k = idx >> 9, c = idx & 511;
    ncll[k * 513 + c] = ncl[idx];
  }
  int k = t & 31, cg = t >> 5;
  for (int r = 0; r < 32; ++r) {
    int n = blockIdx.x * 32 + r;
    __syncthreads();
    for (int c = t; c < CDIM; c += 256) row[c] = merged[(size_t)n * CDIM + c];
    __syncthreads();
    float p = 0.f;
    if (k < KCL) {
      const float* nr = &ncll[k * 513 + cg * 64];
      const float* rr = &row[cg * 64];
#pragma unroll
      for (int i = 0; i < 64; ++i) p += rr[i] * nr[i];
    }
    partial[k][cg] = p;
    __syncthreads();
    if (t < KCL) {
      float v = 0.f;
#pragma unroll
      for (int g = 0; g < 8; ++g) v += partial[t][g];
      innerl[t] = v;
    }
    __syncthreads();
    float mi = 0.f, ml = 0.f, myl = 0.f;
    if (t < KCL) {
      mi = -3.4e38f; ml = -3.4e38f;
      for (int k2 = 0; k2 < KCL; ++k2) {
        float iv = innerl[k2];
        mi = fmaxf(mi, iv);
        ml = fmaxf(ml, iv * alpha);
      }
      myl = innerl[t] * alpha;
      exps[t] = expf(myl - ml);
    }
    __syncthreads();
    if (t < KCL) {
      float sum = 0.f;
      for (int k2 = 0; k2 < KCL; ++k2) sum += exps[k2];
      float sv = exps[t] / sum;
      s[(size_t)n * KCL + t] = sv;
      sT[(size_t)t * NTOT + n] = sv;
      int b = n >> 12, w = (n >> 6) & 63, h = n & 63;
      out_cp[(((size_t)b * KCL + t) * 64 + h) * 64 + w] = myl - (ml + logf(sum));
      if (t == 0) maxv[n] = mi;
    }
  }
}

// ---------------- K4: P strip = relu(M M^T) (diag->0), store bf16 ----------------
__global__ __launch_bounds__(256) void k_gemm1(const float* __restrict__ merged,
    unsigned short* __restrict__ P, int J0base, int JS) {
  __shared__ float As[64 * 33];
  __shared__ float Bs[64 * 33];
  int I0 = blockIdx.x * 64;
  int J0 = J0base + blockIdx.y * 64;
  int t = threadIdx.x;
  int ti = t >> 4, tj = t & 15;
  int li = t >> 2, lk = (t & 3) * 8;
  float acc[4][4] = {{0.f, 0.f, 0.f, 0.f}, {0.f, 0.f, 0.f, 0.f},
                     {0.f, 0.f, 0.f, 0.f}, {0.f, 0.f, 0.f, 0.f}};
  const float* Ag = &merged[(size_t)(I0 + li) * CDIM + lk];
  const float* Bg = &merged[(size_t)(J0 + li) * CDIM + lk];
  for (int kc = 0; kc < CDIM; kc += 32) {
    float4 a0 = *(const float4*)(Ag + kc);
    float4 a1 = *(const float4*)(Ag + kc + 4);
    float4 b0 = *(const float4*)(Bg + kc);
    float4 b1 = *(const float4*)(Bg + kc + 4);
    __syncthreads();
    float* as = &As[li * 33 + lk];
    as[0] = a0.x; as[1] = a0.y; as[2] = a0.z; as[3] = a0.w;
    as[4] = a1.x; as[5] = a1.y; as[6] = a1.z; as[7] = a1.w;
    float* bs = &Bs[li * 33 + lk];
    bs[0] = b0.x; bs[1] = b0.y; bs[2] = b0.z; bs[3] = b0.w;
    bs[4] = b1.x; bs[5] = b1.y; bs[6] = b1.z; bs[7] = b1.w;
    __syncthreads();
#pragma unroll
    for (int kk = 0; kk < 32; ++kk) {
      float av[4], bv[4];
#pragma unroll
      for (int r2 = 0; r2 < 4; ++r2) av[r2] = As[(ti * 4 + r2) * 33 + kk];
#pragma unroll
      for (int r2 = 0; r2 < 4; ++r2) bv[r2] = Bs[(tj * 4 + r2) * 33 + kk];
#pragma unroll
      for (int r2 = 0; r2 < 4; ++r2)
#pragma unroll
        for (int q = 0; q < 4; ++q) acc[r2][q] += av[r2] * bv[q];
    }
  }
#pragma unroll
  for (int r2 = 0; r2 < 4; ++r2) {
    int gi = I0 + ti * 4 + r2;
    int cbase = (J0 - J0base) + tj * 4;
    unsigned short hh[4];
#pragma unroll
    for (int q = 0; q < 4; ++q) {
      float v = acc[r2][q];
      v = v > 0.f ? v : 0.f;
      if (gi == J0 + tj * 4 + q) v = 0.f;  // zero diagonal
      hh[q] = f2bf(v);
    }
    ushort4 pk; pk.x = hh[0]; pk.y = hh[1]; pk.z = hh[2]; pk.w = hh[3];
    *reinterpret_cast<ushort4*>(&P[(size_t)gi * JS + cbase]) = pk;
  }
}

// ---------------- K5: R[N][28] += P_strip @ [1 | S_strip] ----------------
__global__ __launch_bounds__(256) void k_gemm2(const unsigned short* __restrict__ P,
    const float* __restrict__ s, float* __restrict__ R, int J0base, int JS) {
  __shared__ float Pl[64 * 65];
  __shared__ float Sl[64 * 28];
  int I0 = blockIdx.x * 64;
  int t = threadIdx.x;
  int i = t >> 2, kg = t & 3;
  float acc[7] = {0.f, 0.f, 0.f, 0.f, 0.f, 0.f, 0.f};
  for (int j0 = 0; j0 < JS; j0 += 64) {
    __syncthreads();
    const uint4* pp = reinterpret_cast<const uint4*>(P + (size_t)(I0 + i) * JS + j0 + kg * 16);
    uint4 u0 = pp[0], u1 = pp[1];
    unsigned uu[8] = {u0.x, u0.y, u0.z, u0.w, u1.x, u1.y, u1.z, u1.w};
    float* dst = &Pl[i * 65 + kg * 16];
#pragma unroll
    for (int q = 0; q < 8; ++q) {
      union { unsigned u; float f; } lo, hi;
      lo.u = uu[q] << 16;
      hi.u = uu[q] & 0xFFFF0000u;
      dst[2 * q] = lo.f;
      dst[2 * q + 1] = hi.f;
    }
    for (int idx = t; idx < 64 * 28; idx += 256) {
      int jj = idx / 28, col = idx - jj * 28;
      int gj = J0base + j0 + jj;
      Sl[idx] = (col == 0) ? 1.f : s[(size_t)gj * KCL + (col - 1)];
    }
    __syncthreads();
#pragma unroll 8
    for (int jj = 0; jj < 64; ++jj) {
      float p = Pl[i * 65 + jj];
#pragma unroll
      for (int q = 0; q < 7; ++q) acc[q] += p * Sl[jj * 28 + kg * 7 + q];
    }
  }
#pragma unroll
  for (int q = 0; q < 7; ++q)
    R[(size_t)(I0 + i) * 28 + kg * 7 + q] += acc[q];
}

// ---------------- K6: StS[27][27] = S^T S (via sT rows) ----------------
__global__ void k_sts(const float* __restrict__ sT, float* __restrict__ StS) {
  int k = blockIdx.x / KCL, l = blockIdx.x % KCL;
  int t = threadIdx.x; // 256
  const float* a = sT + (size_t)k * NTOT;
  const float* b = sT + (size_t)l * NTOT;
  float acc = 0.f;
  for (int n = t; n < NTOT; n += 256) acc += a[n] * b[n];
  for (int o = 32; o; o >>= 1) acc += __shfl_down(acc, o);
  __shared__ float sc[4];
  if ((t & 63) == 0) sc[t >> 6] = acc;
  __syncthreads();
  if (t == 0) StS[blockIdx.x] = sc[0] + sc[1] + sc[2] + sc[3];
}

// ---------------- K7: final reductions + losses ----------------
__device__ float block_sum_1024(float v) {
  __shared__ float sc[16];
  for (int o = 32; o; o >>= 1) v += __shfl_down(v, o);
  __syncthreads();
  if ((threadIdx.x & 63) == 0) sc[threadIdx.x >> 6] = v;
  __syncthreads();
  if (threadIdx.x == 0) {
    float r = 0.f;
    for (int i = 0; i < 16; ++i) r += sc[i];
    sc[0] = r;
  }
  __syncthreads();
  return sc[0];
}

__global__ __launch_bounds__(1024) void k_final(const float* __restrict__ R,
    const float* __restrict__ s, const float* __restrict__ maxv,
    const float* __restrict__ StS, float* __restrict__ out) {
  int t = threadIdx.x;
  float sumDeg = 0.f, T1 = 0.f, maxsum = 0.f;
  float v[KCL];
#pragma unroll
  for (int k = 0; k < KCL; ++k) v[k] = 0.f;
  for (int n = t; n < NTOT; n += 1024) {
    const float* Rr = R + (size_t)n * 28;
    const float* sr = s + (size_t)n * KCL;
    float deg = Rr[0];
    sumDeg += deg;
    maxsum += maxv[n];
#pragma unroll
    for (int k = 0; k < KCL; ++k) {
      float sv = sr[k];
      T1 += sv * Rr[1 + k];
      v[k] += deg * sv;
    }
  }
#pragma unroll
  for (int k = 0; k < KCL; ++k)
    for (int o = 32; o; o >>= 1) v[k] += __shfl_down(v[k], o);
  __shared__ float vpart[16][KCL];
  __shared__ float vfin[KCL];
  if ((t & 63) == 0)
    for (int k = 0; k < KCL; ++k) vpart[t >> 6][k] = v[k];
  float sumDeg_t = block_sum_1024(sumDeg);
  float T1_t = block_sum_1024(T1);
  float maxsum_t = block_sum_1024(maxsum);
  __syncthreads();
  if (t < KCL) {
    float a = 0.f;
    for (int wv = 0; wv < 16; ++wv) a += vpart[wv][t];
    vfin[t] = a;
  }
  __syncthreads();
  float val = (t < 729) ? StS[t] : 0.f;
  float F2 = block_sum_1024(val * val);
  float F = sqrtf(F2);
  bool diag = (t < 729) && (t % 28 == 0);
  float g = (t < 729) ? (val / F - (diag ? (1.f / sqrtf(27.f)) : 0.f)) : 0.f;
  float O2 = block_sum_1024(g * g);
  float ortho = sqrtf(O2);
  if (t == 0) {
    float norm = 0.5f * sumDeg_t;
    float vv = 0.f;
    for (int k = 0; k < KCL; ++k) vv += vfin[k] * vfin[k];
    float c = 0.05f / (2.f * norm);
    float sm = -(T1_t - c * vv) / (2.f * norm);
    float cl = -maxsum_t / (float)NTOT;
    out[0] = sm + cl + ortho;
    out[1] = sm;
  }
}

extern "C" void kernel_launch(void* const* d_in, const int* in_sizes, int n_in,
                              void* d_out, int out_size, void* d_ws, size_t ws_size,
                              hipStream_t stream) {
  const float* x        = (const float*)d_in[0];
  const float* clusters = (const float*)d_in[1];
  const float* alpha    = (const float*)d_in[2];
  float* out = (float*)d_out;
  float* ws  = (float*)d_ws;

  // workspace layout (float offsets)
  const size_t OFF_MERGED = 0;
  const size_t OFF_NCL  = (size_t)NTOT * CDIM;             // 4,194,304
  const size_t OFF_S    = OFF_NCL + (size_t)KCL * CDIM;
  const size_t OFF_ST   = OFF_S + (size_t)NTOT * KCL;
  const size_t OFF_MAXV = OFF_ST + (size_t)NTOT * KCL;
  const size_t OFF_R    = OFF_MAXV + NTOT;
  const size_t OFF_STS  = OFF_R + (size_t)NTOT * 28;
  size_t off_p = ((OFF_STS + 729 + 15) / 16) * 16;         // P (bf16) starts here

  int JS = 256;
  const int cands[5] = {8192, 2048, 1024, 512, 256};
  for (int ci = 0; ci < 5; ++ci) {
    size_t need = off_p * 4 + (size_t)NTOT * (size_t)cands[ci] * 2;
    if (need <= ws_size) { JS = cands[ci]; break; }
  }

  hipMemsetAsync(ws + OFF_R, 0, (size_t)NTOT * 28 * sizeof(float), stream);
  k_norm_clusters<<<27, 64, 0, stream>>>(clusters, ws + OFF_NCL);
  k_merged<<<128, 256, 0, stream>>>(x, ws + OFF_MERGED);
  k_inner<<<256, 256, 0, stream>>>(ws + OFF_MERGED, ws + OFF_NCL, alpha,
                                   ws + OFF_S, ws + OFF_ST, ws + OFF_MAXV, out + 2);
  unsigned short* P = (unsigned short*)(ws + off_p);
  int nstr = NTOT / JS;
  for (int st = 0; st < nstr; ++st) {
    k_gemm1<<<dim3(128, JS / 64), 256, 0, stream>>>(ws + OFF_MERGED, P, st * JS, JS);
    k_gemm2<<<128, 256, 0, stream>>>(P, ws + OFF_S, ws + OFF_R, st * JS, JS);
  }
  k_sts<<<729, 256, 0, stream>>>(ws + OFF_ST, ws + OFF_STS);
  k_final<<<1, 1024, 0, stream>>>(ws + OFF_R, ws + OFF_S, ws + OFF_MAXV,
                                  ws + OFF_STS, out);
}

// Round 2
// 554.150 us; speedup vs baseline: 4.0290x; 4.0290x over previous
//
#include <hip/hip_runtime.h>

#define NTOT 8192
#define CDIM 512
#define KCL 27

typedef __attribute__((ext_vector_type(8))) short short8;
typedef __attribute__((ext_vector_type(4))) float f32x4;

static __device__ __forceinline__ unsigned short f2bf(float v) {
  union { float f; unsigned u; } z; z.f = v;
  unsigned r = (z.u + 0x7FFFu + ((z.u >> 16) & 1u)) >> 16;
  return (unsigned short)r;
}

// ---------------- K1: normalize clusters (27 x 512) ----------------
__global__ void k_norm_clusters(const float* __restrict__ cl, float* __restrict__ ncl) {
  int k = blockIdx.x;
  int t = threadIdx.x; // 64
  const float* row = cl + (size_t)k * CDIM;
  float ss = 0.f;
  for (int c = t; c < CDIM; c += 64) { float v = row[c]; ss += v * v; }
  for (int o = 32; o; o >>= 1) ss += __shfl_down(ss, o);
  ss = __shfl(ss, 0);
  float inv = 1.f / fmaxf(sqrtf(ss), 1e-12f);
  for (int c = t; c < CDIM; c += 64) ncl[(size_t)k * CDIM + c] = row[c] * inv;
}

// ---------------- K2: per-pixel L2 norm + permute(0,3,2,1) -> merged[N][C] (f32 + bf16) ----------------
__global__ __launch_bounds__(256) void k_merged(const float* __restrict__ x,
    float* __restrict__ merged, unsigned short* __restrict__ mbf) {
  __shared__ float inv[64];
  __shared__ float part[4][64];
  __shared__ float tile[64][65];
  int bh = blockIdx.x;           // b*64 + h
  int b = bh >> 6, h = bh & 63;
  int t = threadIdx.x;
  int w = t & 63, cg = t >> 6;
  const float* xb = x + (size_t)b * CDIM * 4096 + (size_t)h * 64; // xb[c*4096 + w]
  float ss = 0.f;
  for (int c = cg; c < CDIM; c += 4) {
    float v = xb[(size_t)c * 4096 + w];
    ss += v * v;
  }
  part[cg][w] = ss;
  __syncthreads();
  if (t < 64) {
    float s2 = part[0][t] + part[1][t] + part[2][t] + part[3][t];
    inv[t] = 1.f / fmaxf(sqrtf(s2), 1e-12f);
  }
  __syncthreads();
  for (int c0 = 0; c0 < CDIM; c0 += 64) {
#pragma unroll
    for (int q = 0; q < 16; ++q) {
      int c = cg + q * 4;
      tile[c][w] = xb[(size_t)(c0 + c) * 4096 + w];
    }
    __syncthreads();
#pragma unroll
    for (int q = 0; q < 16; ++q) {
      int ww = cg + q * 4;
      int n = b * 4096 + ww * 64 + h;          // n from permute(0,3,2,1)
      float v = tile[w][ww] * inv[ww];
      merged[(size_t)n * CDIM + c0 + w] = v;
      mbf[(size_t)n * CDIM + c0 + w] = f2bf(v);
    }
    __syncthreads();
  }
}

// ---------------- K3: inner vs clusters, softmax, log_softmax out, max, s, sT ----------------
__global__ __launch_bounds__(256) void k_inner(const float* __restrict__ merged,
    const float* __restrict__ ncl, const float* __restrict__ alpha_p,
    float* __restrict__ s, float* __restrict__ sT, float* __restrict__ maxv,
    float* __restrict__ out_cp) {
  __shared__ float ncll[KCL * 513];
  __shared__ float row[CDIM];
  __shared__ float partial[32][8];
  __shared__ float innerl[KCL];
  __shared__ float exps[KCL];
  int t = threadIdx.x;
  float alpha = alpha_p[0];
  for (int idx = t; idx < KCL * CDIM; idx += 256) {
    int k = idx >> 9, c = idx & 511;
    ncll[k * 513 + c] = ncl[idx];
  }
  int k = t & 31, cg = t >> 5;
  for (int r = 0; r < 8; ++r) {
    int n = blockIdx.x * 8 + r;
    __syncthreads();
    for (int c = t; c < CDIM; c += 256) row[c] = merged[(size_t)n * CDIM + c];
    __syncthreads();
    float p = 0.f;
    if (k < KCL) {
      const float* nr = &ncll[k * 513 + cg * 64];
      const float* rr = &row[cg * 64];
#pragma unroll
      for (int i = 0; i < 64; ++i) p += rr[i] * nr[i];
    }
    partial[k][cg] = p;
    __syncthreads();
    if (t < KCL) {
      float v = 0.f;
#pragma unroll
      for (int g = 0; g < 8; ++g) v += partial[t][g];
      innerl[t] = v;
    }
    __syncthreads();
    float mi = 0.f, ml = 0.f, myl = 0.f;
    if (t < KCL) {
      mi = -3.4e38f; ml = -3.4e38f;
      for (int k2 = 0; k2 < KCL; ++k2) {
        float iv = innerl[k2];
        mi = fmaxf(mi, iv);
        ml = fmaxf(ml, iv * alpha);
      }
      myl = innerl[t] * alpha;
      exps[t] = expf(myl - ml);
    }
    __syncthreads();
    if (t < KCL) {
      float sum = 0.f;
      for (int k2 = 0; k2 < KCL; ++k2) sum += exps[k2];
      float sv = exps[t] / sum;
      s[(size_t)n * KCL + t] = sv;
      sT[(size_t)t * NTOT + n] = sv;
      int b = n >> 12, w = (n >> 6) & 63, h = n & 63;
      out_cp[(((size_t)b * KCL + t) * 64 + h) * 64 + w] = myl - (ml + logf(sum));
      if (t == 0) maxv[n] = mi;
    }
  }
}

// ---------------- K4 (MFMA): P tile = relu(Mb Mb^T) (diag->0), store bf16 ----------------
// m97 structure: 128x128 tile, BK=32, 4 waves (2x2), 16x16x32 bf16 MFMA,
// global_load_lds width=16 staging, ds_read_b128 fragments.
__global__ __launch_bounds__(256) void k_gemm1(const unsigned short* __restrict__ Mb,
    unsigned short* __restrict__ P, int J0base, int JS) {
  __shared__ char lds[16384];           // As[128][32] bf16 | Bs[128][32] bf16
  char* As = lds;
  char* Bs = lds + 8192;
  int t = threadIdx.x;
  int wid = t >> 6, lane = t & 63;
  int wr = wid >> 1, wc = wid & 1;      // 2x2 wave grid, 64x64 each
  int r15 = lane & 15, kgrp = lane >> 4;
  int I0 = blockIdx.x * 128;
  int J0 = J0base + blockIdx.y * 128;

  f32x4 acc[4][4];
#pragma unroll
  for (int m = 0; m < 4; ++m)
#pragma unroll
    for (int n = 0; n < 4; ++n) acc[m][n] = (f32x4){0.f, 0.f, 0.f, 0.f};

  // staging: lds byte off = c*4096 + wid*1024 + lane*16
  //   -> row = c*64 + wid*16 + lane/4, kcol = (lane&3)*8
  int srow = wid * 16 + (lane >> 2);
  int scol = (lane & 3) * 8;
  const unsigned short* gA0 = Mb + (size_t)(I0 + srow) * CDIM + scol;
  const unsigned short* gA1 = Mb + (size_t)(I0 + 64 + srow) * CDIM + scol;
  const unsigned short* gB0 = Mb + (size_t)(J0 + srow) * CDIM + scol;
  const unsigned short* gB1 = Mb + (size_t)(J0 + 64 + srow) * CDIM + scol;
  char* lA0 = As + wid * 1024;          // wave-uniform LDS bases
  char* lA1 = As + 4096 + wid * 1024;
  char* lB0 = Bs + wid * 1024;
  char* lB1 = Bs + 4096 + wid * 1024;

  for (int k0 = 0; k0 < CDIM; k0 += 32) {
    __builtin_amdgcn_global_load_lds(
        (const __attribute__((address_space(1))) void*)(gA0 + k0),
        (__attribute__((address_space(3))) void*)lA0, 16, 0, 0);
    __builtin_amdgcn_global_load_lds(
        (const __attribute__((address_space(1))) void*)(gA1 + k0),
        (__attribute__((address_space(3))) void*)lA1, 16, 0, 0);
    __builtin_amdgcn_global_load_lds(
        (const __attribute__((address_space(1))) void*)(gB0 + k0),
        (__attribute__((address_space(3))) void*)lB0, 16, 0, 0);
    __builtin_amdgcn_global_load_lds(
        (const __attribute__((address_space(1))) void*)(gB1 + k0),
        (__attribute__((address_space(3))) void*)lB1, 16, 0, 0);
    __syncthreads();   // drains vmcnt: staged data visible

    short8 a[4], b[4];
#pragma unroll
    for (int m = 0; m < 4; ++m)
      a[m] = *(const short8*)(As + ((wr * 64 + m * 16 + r15) * 64 + kgrp * 16));
#pragma unroll
    for (int n = 0; n < 4; ++n)
      b[n] = *(const short8*)(Bs + ((wc * 64 + n * 16 + r15) * 64 + kgrp * 16));
#pragma unroll
    for (int m = 0; m < 4; ++m)
#pragma unroll
      for (int n = 0; n < 4; ++n)
        acc[m][n] = __builtin_amdgcn_mfma_f32_16x16x32_bf16(a[m], b[n], acc[m][n], 0, 0, 0);
    __syncthreads();   // all waves done reading before next stage overwrites
  }

  // epilogue: C/D layout col=lane&15, row=(lane>>4)*4+reg  [m89-verified]
#pragma unroll
  for (int m = 0; m < 4; ++m) {
#pragma unroll
    for (int n = 0; n < 4; ++n) {
      int gi_base = I0 + wr * 64 + m * 16 + kgrp * 4;
      int gj = J0 + wc * 64 + n * 16 + r15;
#pragma unroll
      for (int reg = 0; reg < 4; ++reg) {
        int gi = gi_base + reg;
        float v = acc[m][n][reg];
        v = v > 0.f ? v : 0.f;
        if (gi == gj) v = 0.f;           // zero diagonal
        P[(size_t)gi * JS + (gj - J0base)] = f2bf(v);
      }
    }
  }
}

// ---------------- K5: Rpart[split][N][28] += P_strip @ [1 | S_strip] ----------------
__global__ __launch_bounds__(256) void k_gemm2(const unsigned short* __restrict__ P,
    const float* __restrict__ s, float* __restrict__ Rpart, int J0base, int JS) {
  __shared__ float Pl[64 * 65];
  __shared__ float Sl[64 * 28];
  int I0 = blockIdx.x * 64;
  int cs = JS / 4;                       // columns per split
  int jbeg = blockIdx.y * cs;
  int t = threadIdx.x;
  int i = t >> 2, kg = t & 3;
  float acc[7] = {0.f, 0.f, 0.f, 0.f, 0.f, 0.f, 0.f};
  for (int j0 = jbeg; j0 < jbeg + cs; j0 += 64) {
    __syncthreads();
    const uint4* pp = reinterpret_cast<const uint4*>(P + (size_t)(I0 + i) * JS + j0 + kg * 16);
    uint4 u0 = pp[0], u1 = pp[1];
    unsigned uu[8] = {u0.x, u0.y, u0.z, u0.w, u1.x, u1.y, u1.z, u1.w};
    float* dst = &Pl[i * 65 + kg * 16];
#pragma unroll
    for (int q = 0; q < 8; ++q) {
      union { unsigned u; float f; } lo, hi;
      lo.u = uu[q] << 16;
      hi.u = uu[q] & 0xFFFF0000u;
      dst[2 * q] = lo.f;
      dst[2 * q + 1] = hi.f;
    }
    for (int idx = t; idx < 64 * 28; idx += 256) {
      int jj = idx / 28, col = idx - jj * 28;
      int gj = J0base + j0 + jj;
      Sl[idx] = (col == 0) ? 1.f : s[(size_t)gj * KCL + (col - 1)];
    }
    __syncthreads();
#pragma unroll 8
    for (int jj = 0; jj < 64; ++jj) {
      float p = Pl[i * 65 + jj];
#pragma unroll
      for (int q = 0; q < 7; ++q) acc[q] += p * Sl[jj * 28 + kg * 7 + q];
    }
  }
  float* dst = Rpart + ((size_t)blockIdx.y * NTOT + I0 + i) * 28 + kg * 7;
#pragma unroll
  for (int q = 0; q < 7; ++q) dst[q] += acc[q];
}

// ---------------- K6: StS[27][27] = S^T S (via sT rows) ----------------
__global__ void k_sts(const float* __restrict__ sT, float* __restrict__ StS) {
  int k = blockIdx.x / KCL, l = blockIdx.x % KCL;
  int t = threadIdx.x; // 256
  const float* a = sT + (size_t)k * NTOT;
  const float* b = sT + (size_t)l * NTOT;
  float acc = 0.f;
  for (int n = t; n < NTOT; n += 256) acc += a[n] * b[n];
  for (int o = 32; o; o >>= 1) acc += __shfl_down(acc, o);
  __shared__ float sc[4];
  if ((t & 63) == 0) sc[t >> 6] = acc;
  __syncthreads();
  if (t == 0) StS[blockIdx.x] = sc[0] + sc[1] + sc[2] + sc[3];
}

// ---------------- K7: final reductions + losses ----------------
__device__ float block_sum_1024(float v) {
  __shared__ float sc[16];
  for (int o = 32; o; o >>= 1) v += __shfl_down(v, o);
  __syncthreads();
  if ((threadIdx.x & 63) == 0) sc[threadIdx.x >> 6] = v;
  __syncthreads();
  if (threadIdx.x == 0) {
    float r = 0.f;
    for (int i = 0; i < 16; ++i) r += sc[i];
    sc[0] = r;
  }
  __syncthreads();
  return sc[0];
}

__global__ __launch_bounds__(1024) void k_final(const float* __restrict__ Rpart,
    const float* __restrict__ s, const float* __restrict__ maxv,
    const float* __restrict__ StS, float* __restrict__ out) {
  int t = threadIdx.x;
  float sumDeg = 0.f, T1 = 0.f, maxsum = 0.f;
  float v[KCL];
#pragma unroll
  for (int k = 0; k < KCL; ++k) v[k] = 0.f;
  for (int n = t; n < NTOT; n += 1024) {
    float rsum[28];
#pragma unroll
    for (int c = 0; c < 28; ++c) rsum[c] = 0.f;
#pragma unroll
    for (int bs = 0; bs < 4; ++bs) {
      const float* Rr = Rpart + ((size_t)bs * NTOT + n) * 28;
#pragma unroll
      for (int c = 0; c < 28; ++c) rsum[c] += Rr[c];
    }
    const float* sr = s + (size_t)n * KCL;
    float deg = rsum[0];
    sumDeg += deg;
    maxsum += maxv[n];
#pragma unroll
    for (int k = 0; k < KCL; ++k) {
      float sv = sr[k];
      T1 += sv * rsum[1 + k];
      v[k] += deg * sv;
    }
  }
#pragma unroll
  for (int k = 0; k < KCL; ++k)
    for (int o = 32; o; o >>= 1) v[k] += __shfl_down(v[k], o);
  __shared__ float vpart[16][KCL];
  __shared__ float vfin[KCL];
  if ((t & 63) == 0)
    for (int k = 0; k < KCL; ++k) vpart[t >> 6][k] = v[k];
  float sumDeg_t = block_sum_1024(sumDeg);
  float T1_t = block_sum_1024(T1);
  float maxsum_t = block_sum_1024(maxsum);
  __syncthreads();
  if (t < KCL) {
    float a = 0.f;
    for (int wv = 0; wv < 16; ++wv) a += vpart[wv][t];
    vfin[t] = a;
  }
  __syncthreads();
  float val = (t < 729) ? StS[t] : 0.f;
  float F2 = block_sum_1024(val * val);
  float F = sqrtf(F2);
  bool diag = (t < 729) && (t % 28 == 0);
  float g = (t < 729) ? (val / F - (diag ? (1.f / sqrtf(27.f)) : 0.f)) : 0.f;
  float O2 = block_sum_1024(g * g);
  float ortho = sqrtf(O2);
  if (t == 0) {
    float norm = 0.5f * sumDeg_t;
    float vv = 0.f;
    for (int k = 0; k < KCL; ++k) vv += vfin[k] * vfin[k];
    float c = 0.05f / (2.f * norm);
    float sm = -(T1_t - c * vv) / (2.f * norm);
    float cl = -maxsum_t / (float)NTOT;
    out[0] = sm + cl + ortho;
    out[1] = sm;
  }
}

extern "C" void kernel_launch(void* const* d_in, const int* in_sizes, int n_in,
                              void* d_out, int out_size, void* d_ws, size_t ws_size,
                              hipStream_t stream) {
  const float* x        = (const float*)d_in[0];
  const float* clusters = (const float*)d_in[1];
  const float* alpha    = (const float*)d_in[2];
  float* out = (float*)d_out;
  float* ws  = (float*)d_ws;

  // workspace layout (float offsets)
  const size_t OFF_MERGED = 0;                                  // 8192*512 f32
  const size_t OFF_MBF  = (size_t)NTOT * CDIM;                  // 8192*512 bf16 (2,097,152 f32)
  const size_t OFF_NCL  = OFF_MBF + (size_t)NTOT * CDIM / 2;
  const size_t OFF_S    = OFF_NCL + (size_t)KCL * CDIM;
  const size_t OFF_ST   = OFF_S + (size_t)NTOT * KCL;
  const size_t OFF_MAXV = OFF_ST + (size_t)NTOT * KCL;
  const size_t OFF_R    = OFF_MAXV + NTOT;                      // Rpart: 4*8192*28
  const size_t OFF_STS  = OFF_R + (size_t)4 * NTOT * 28;
  size_t off_p = ((OFF_STS + 729 + 15) / 16) * 16;              // P (bf16) starts here

  int JS = 256;
  const int cands[5] = {8192, 2048, 1024, 512, 256};
  for (int ci = 0; ci < 5; ++ci) {
    size_t need = off_p * 4 + (size_t)NTOT * (size_t)cands[ci] * 2;
    if (need <= ws_size) { JS = cands[ci]; break; }
  }

  unsigned short* mbf = (unsigned short*)(ws + OFF_MBF);
  hipMemsetAsync(ws + OFF_R, 0, (size_t)4 * NTOT * 28 * sizeof(float), stream);
  k_norm_clusters<<<27, 64, 0, stream>>>(clusters, ws + OFF_NCL);
  k_merged<<<128, 256, 0, stream>>>(x, ws + OFF_MERGED, mbf);
  k_inner<<<1024, 256, 0, stream>>>(ws + OFF_MERGED, ws + OFF_NCL, alpha,
                                    ws + OFF_S, ws + OFF_ST, ws + OFF_MAXV, out + 2);
  unsigned short* P = (unsigned short*)(ws + off_p);
  int nstr = NTOT / JS;
  for (int st = 0; st < nstr; ++st) {
    k_gemm1<<<dim3(64, JS / 128), 256, 0, stream>>>(mbf, P, st * JS, JS);
    k_gemm2<<<dim3(128, 4), 256, 0, stream>>>(P, ws + OFF_S, ws + OFF_R, st * JS, JS);
  }
  k_sts<<<729, 256, 0, stream>>>(ws + OFF_ST, ws + OFF_STS);
  k_final<<<1, 1024, 0, stream>>>(ws + OFF_R, ws + OFF_S, ws + OFF_MAXV,
                                  ws + OFF_STS, out);
}

// Round 3
// 494.254 us; speedup vs baseline: 4.5173x; 1.1212x over previous
//
#include <hip/hip_runtime.h>

#define NTOT 8192
#define CDIM 512
#define KCL 27

typedef __attribute__((ext_vector_type(8))) short short8;
typedef __attribute__((ext_vector_type(4))) float f32x4;

static __device__ __forceinline__ unsigned short f2bf(float v) {
  union { float f; unsigned u; } z; z.f = v;
  unsigned r = (z.u + 0x7FFFu + ((z.u >> 16) & 1u)) >> 16;
  return (unsigned short)r;
}

// ---------------- K1: normalize clusters (27 x 512) ----------------
__global__ void k_norm_clusters(const float* __restrict__ cl, float* __restrict__ ncl) {
  int k = blockIdx.x;
  int t = threadIdx.x; // 64
  const float* row = cl + (size_t)k * CDIM;
  float ss = 0.f;
  for (int c = t; c < CDIM; c += 64) { float v = row[c]; ss += v * v; }
  for (int o = 32; o; o >>= 1) ss += __shfl_down(ss, o);
  ss = __shfl(ss, 0);
  float inv = 1.f / fmaxf(sqrtf(ss), 1e-12f);
  for (int c = t; c < CDIM; c += 64) ncl[(size_t)k * CDIM + c] = row[c] * inv;
}

// ---------------- K2: per-pixel L2 norm + permute(0,3,2,1) -> merged[N][C] (f32 + bf16) ----------------
__global__ __launch_bounds__(256) void k_merged(const float* __restrict__ x,
    float* __restrict__ merged, unsigned short* __restrict__ mbf) {
  __shared__ float inv[64];
  __shared__ float part[4][64];
  __shared__ float tile[64][65];
  int bh = blockIdx.x;           // b*64 + h
  int b = bh >> 6, h = bh & 63;
  int t = threadIdx.x;
  int w = t & 63, cg = t >> 6;
  const float* xb = x + (size_t)b * CDIM * 4096 + (size_t)h * 64; // xb[c*4096 + w]
  float ss = 0.f;
  for (int c = cg; c < CDIM; c += 4) {
    float v = xb[(size_t)c * 4096 + w];
    ss += v * v;
  }
  part[cg][w] = ss;
  __syncthreads();
  if (t < 64) {
    float s2 = part[0][t] + part[1][t] + part[2][t] + part[3][t];
    inv[t] = 1.f / fmaxf(sqrtf(s2), 1e-12f);
  }
  __syncthreads();
  for (int c0 = 0; c0 < CDIM; c0 += 64) {
#pragma unroll
    for (int q = 0; q < 16; ++q) {
      int c = cg + q * 4;
      tile[c][w] = xb[(size_t)(c0 + c) * 4096 + w];
    }
    __syncthreads();
#pragma unroll
    for (int q = 0; q < 16; ++q) {
      int ww = cg + q * 4;
      int n = b * 4096 + ww * 64 + h;          // n from permute(0,3,2,1)
      float v = tile[w][ww] * inv[ww];
      merged[(size_t)n * CDIM + c0 + w] = v;
      mbf[(size_t)n * CDIM + c0 + w] = f2bf(v);
    }
    __syncthreads();
  }
}

// ---------------- K3: inner vs clusters, softmax, log_softmax out, max, s, sT, sxT(bf16) ----------------
__global__ __launch_bounds__(256) void k_inner(const float* __restrict__ merged,
    const float* __restrict__ ncl, const float* __restrict__ alpha_p,
    float* __restrict__ s, float* __restrict__ sT, float* __restrict__ maxv,
    float* __restrict__ out_cp, unsigned short* __restrict__ sxbf) {
  __shared__ float ncll[KCL * 513];
  __shared__ float row[CDIM];
  __shared__ float partial[32][8];
  __shared__ float innerl[KCL];
  __shared__ float exps[KCL];
  int t = threadIdx.x;
  float alpha = alpha_p[0];
  for (int idx = t; idx < KCL * CDIM; idx += 256) {
    int k = idx >> 9, c = idx & 511;
    ncll[k * 513 + c] = ncl[idx];
  }
  int k = t & 31, cg = t >> 5;
  for (int r = 0; r < 8; ++r) {
    int n = blockIdx.x * 8 + r;
    __syncthreads();
    for (int c = t; c < CDIM; c += 256) row[c] = merged[(size_t)n * CDIM + c];
    __syncthreads();
    float p = 0.f;
    if (k < KCL) {
      const float* nr = &ncll[k * 513 + cg * 64];
      const float* rr = &row[cg * 64];
#pragma unroll
      for (int i = 0; i < 64; ++i) p += rr[i] * nr[i];
    }
    partial[k][cg] = p;
    __syncthreads();
    if (t < KCL) {
      float v = 0.f;
#pragma unroll
      for (int g = 0; g < 8; ++g) v += partial[t][g];
      innerl[t] = v;
    }
    __syncthreads();
    float mi = 0.f, ml = 0.f, myl = 0.f;
    if (t < KCL) {
      mi = -3.4e38f; ml = -3.4e38f;
      for (int k2 = 0; k2 < KCL; ++k2) {
        float iv = innerl[k2];
        mi = fmaxf(mi, iv);
        ml = fmaxf(ml, iv * alpha);
      }
      myl = innerl[t] * alpha;
      exps[t] = expf(myl - ml);
    }
    __syncthreads();
    if (t < KCL) {
      float sum = 0.f;
      for (int k2 = 0; k2 < KCL; ++k2) sum += exps[k2];
      float sv = exps[t] / sum;
      s[(size_t)n * KCL + t] = sv;
      sT[(size_t)t * NTOT + n] = sv;
      sxbf[(size_t)(t + 1) * NTOT + n] = f2bf(sv);   // Sx rows 1..27
      int b = n >> 12, w = (n >> 6) & 63, h = n & 63;
      out_cp[(((size_t)b * KCL + t) * 64 + h) * 64 + w] = myl - (ml + logf(sum));
      if (t == 0) { maxv[n] = mi; sxbf[n] = 0x3F80; } // Sx row 0 = 1.0
    }
  }
}

// ---------------- K4 (fused): Rpart[jc] = relu(Mi Mj^T, diag=0) @ [1|S], no P in global ----------------
// Per block: i-tile 128 rows, j-chunk 1024 cols (8 j-tiles of 128).
// P-tile via swapped MFMA (acc holds P^T: lane has 4 j-contiguous) -> packed
// ds_write_b64 into XOR-swizzled row-major-P LDS tile -> second MFMA (PV).
__global__ __launch_bounds__(256) void k_fused(const unsigned short* __restrict__ Mb,
    const unsigned short* __restrict__ sxT, float* __restrict__ Rpart) {
  __shared__ char lds[57344];   // LdsJ 8K | LdsI 8K | Prow 32K | Sx 8K
  char* LdsJ = lds;
  char* LdsI = lds + 8192;
  char* Prow = lds + 16384;
  char* Sx   = lds + 49152;
  int t = threadIdx.x;
  int wid = t >> 6, lane = t & 63;
  int r15 = lane & 15, kgrp = lane >> 4;
  int wrj = wid >> 1, wci = wid & 1;    // j-quadrant / i-quadrant for P-MFMA
  int I0 = blockIdx.x * 128;
  int Jbase = blockIdx.y * 1024;

  f32x4 pv[2][2];
#pragma unroll
  for (int m = 0; m < 2; ++m)
#pragma unroll
    for (int n = 0; n < 2; ++n) pv[m][n] = (f32x4){0.f, 0.f, 0.f, 0.f};

  // staging geometry (m97 pattern): 4 global_load_lds x16B per wave covers 128x32 bf16
  int srow = wid * 16 + (lane >> 2);
  int scol = (lane & 3) * 8;
  char* lJ0 = LdsJ + wid * 1024;
  char* lJ1 = LdsJ + 4096 + wid * 1024;
  char* lI0 = LdsI + wid * 1024;
  char* lI1 = LdsI + 4096 + wid * 1024;
  const unsigned short* gI0 = Mb + (size_t)(I0 + srow) * CDIM + scol;
  const unsigned short* gI1 = Mb + (size_t)(I0 + 64 + srow) * CDIM + scol;

  for (int jt = 0; jt < 8; ++jt) {
    int J0 = Jbase + jt * 128;
    __syncthreads();   // prev PV readers done before Sx/Prow overwrite

    // stage Sx tile [32 c][128 j] bf16, swizzled byte ^= (c&7)<<4
#pragma unroll
    for (int r2 = 0; r2 < 2; ++r2) {
      int c = r2 * 16 + (t >> 4);
      int jsrc = (t & 15) * 8;
      uint4 d = *(const uint4*)(sxT + (size_t)c * NTOT + J0 + jsrc);
      *(uint4*)(Sx + c * 256 + (((t & 15) * 16) ^ ((c & 7) << 4))) = d;
    }

    f32x4 acc[4][4];
#pragma unroll
    for (int m = 0; m < 4; ++m)
#pragma unroll
      for (int n = 0; n < 4; ++n) acc[m][n] = (f32x4){0.f, 0.f, 0.f, 0.f};

    const unsigned short* gJ0 = Mb + (size_t)(J0 + srow) * CDIM + scol;
    const unsigned short* gJ1 = Mb + (size_t)(J0 + 64 + srow) * CDIM + scol;
    for (int k0 = 0; k0 < CDIM; k0 += 32) {
      __builtin_amdgcn_global_load_lds(
          (const __attribute__((address_space(1))) void*)(gJ0 + k0),
          (__attribute__((address_space(3))) void*)lJ0, 16, 0, 0);
      __builtin_amdgcn_global_load_lds(
          (const __attribute__((address_space(1))) void*)(gJ1 + k0),
          (__attribute__((address_space(3))) void*)lJ1, 16, 0, 0);
      __builtin_amdgcn_global_load_lds(
          (const __attribute__((address_space(1))) void*)(gI0 + k0),
          (__attribute__((address_space(3))) void*)lI0, 16, 0, 0);
      __builtin_amdgcn_global_load_lds(
          (const __attribute__((address_space(1))) void*)(gI1 + k0),
          (__attribute__((address_space(3))) void*)lI1, 16, 0, 0);
      __syncthreads();

      short8 a[4], b[4];
#pragma unroll
      for (int m = 0; m < 4; ++m)
        a[m] = *(const short8*)(LdsJ + ((wrj * 64 + m * 16 + r15) * 64 + kgrp * 16));
#pragma unroll
      for (int n = 0; n < 4; ++n)
        b[n] = *(const short8*)(LdsI + ((wci * 64 + n * 16 + r15) * 64 + kgrp * 16));
#pragma unroll
      for (int m = 0; m < 4; ++m)
#pragma unroll
        for (int n = 0; n < 4; ++n)
          acc[m][n] = __builtin_amdgcn_mfma_f32_16x16x32_bf16(a[m], b[n], acc[m][n], 0, 0, 0);
      __syncthreads();
    }

    // acc[m][n] = P^T tile: row j = wrj*64+m*16+kgrp*4+reg, col i = wci*64+n*16+r15.
    // Write row-major P (j contiguous per lane) with relu/diag, bf16 packed b64.
#pragma unroll
    for (int m = 0; m < 4; ++m) {
#pragma unroll
      for (int n = 0; n < 4; ++n) {
        int iloc = wci * 64 + n * 16 + r15;
        int gi = I0 + iloc;
        int jloc = wrj * 64 + m * 16 + kgrp * 4;
        int gj = J0 + jloc;
        unsigned short h[4];
#pragma unroll
        for (int reg = 0; reg < 4; ++reg) {
          float v = acc[m][n][reg];
          v = v > 0.f ? v : 0.f;
          if (gj + reg == gi) v = 0.f;
          h[reg] = f2bf(v);
        }
        uint2 pk;
        pk.x = (unsigned)h[0] | ((unsigned)h[1] << 16);
        pk.y = (unsigned)h[2] | ((unsigned)h[3] << 16);
        *(uint2*)(Prow + iloc * 256 + ((jloc * 2) ^ ((iloc & 7) << 4))) = pk;
      }
    }
    __syncthreads();

    // PV: pv[m2][n2] += Ptile(128x128) @ Sx(128x32); wave owns rows wid*32..+32
#pragma unroll
    for (int ks = 0; ks < 4; ++ks) {
      short8 a2[2], b2[2];
#pragma unroll
      for (int m2 = 0; m2 < 2; ++m2) {
        int iloc = wid * 32 + m2 * 16 + r15;
        a2[m2] = *(const short8*)(Prow + iloc * 256 +
                                  ((ks * 64 + kgrp * 16) ^ ((iloc & 7) << 4)));
      }
#pragma unroll
      for (int n2 = 0; n2 < 2; ++n2) {
        int c = n2 * 16 + r15;
        b2[n2] = *(const short8*)(Sx + c * 256 +
                                  ((ks * 64 + kgrp * 16) ^ ((c & 7) << 4)));
      }
#pragma unroll
      for (int m2 = 0; m2 < 2; ++m2)
#pragma unroll
        for (int n2 = 0; n2 < 2; ++n2)
          pv[m2][n2] = __builtin_amdgcn_mfma_f32_16x16x32_bf16(a2[m2], b2[n2], pv[m2][n2], 0, 0, 0);
    }
  }

  // write Rpart[jc][gi][c]; exclusive per block, no init needed
#pragma unroll
  for (int m2 = 0; m2 < 2; ++m2) {
#pragma unroll
    for (int n2 = 0; n2 < 2; ++n2) {
      int c = n2 * 16 + r15;
      if (c < 28) {
#pragma unroll
        for (int reg = 0; reg < 4; ++reg) {
          int gi = I0 + wid * 32 + m2 * 16 + kgrp * 4 + reg;
          Rpart[((size_t)blockIdx.y * NTOT + gi) * 28 + c] = pv[m2][n2][reg];
        }
      }
    }
  }
}

// ---------------- K6: StS[27][27] = S^T S (via sT rows) ----------------
__global__ void k_sts(const float* __restrict__ sT, float* __restrict__ StS) {
  int k = blockIdx.x / KCL, l = blockIdx.x % KCL;
  int t = threadIdx.x; // 256
  const float* a = sT + (size_t)k * NTOT;
  const float* b = sT + (size_t)l * NTOT;
  float acc = 0.f;
  for (int n = t; n < NTOT; n += 256) acc += a[n] * b[n];
  for (int o = 32; o; o >>= 1) acc += __shfl_down(acc, o);
  __shared__ float sc[4];
  if ((t & 63) == 0) sc[t >> 6] = acc;
  __syncthreads();
  if (t == 0) StS[blockIdx.x] = sc[0] + sc[1] + sc[2] + sc[3];
}

// ---------------- K7: final reductions + losses ----------------
__device__ float block_sum_1024(float v) {
  __shared__ float sc[16];
  for (int o = 32; o; o >>= 1) v += __shfl_down(v, o);
  __syncthreads();
  if ((threadIdx.x & 63) == 0) sc[threadIdx.x >> 6] = v;
  __syncthreads();
  if (threadIdx.x == 0) {
    float r = 0.f;
    for (int i = 0; i < 16; ++i) r += sc[i];
    sc[0] = r;
  }
  __syncthreads();
  return sc[0];
}

__global__ __launch_bounds__(1024) void k_final(const float* __restrict__ Rpart,
    const float* __restrict__ s, const float* __restrict__ maxv,
    const float* __restrict__ StS, float* __restrict__ out) {
  int t = threadIdx.x;
  float sumDeg = 0.f, T1 = 0.f, maxsum = 0.f;
  float v[KCL];
#pragma unroll
  for (int k = 0; k < KCL; ++k) v[k] = 0.f;
  for (int n = t; n < NTOT; n += 1024) {
    float rsum[28];
#pragma unroll
    for (int c = 0; c < 28; ++c) rsum[c] = 0.f;
#pragma unroll
    for (int bs = 0; bs < 8; ++bs) {
      const float* Rr = Rpart + ((size_t)bs * NTOT + n) * 28;
#pragma unroll
      for (int c = 0; c < 28; ++c) rsum[c] += Rr[c];
    }
    const float* sr = s + (size_t)n * KCL;
    float deg = rsum[0];
    sumDeg += deg;
    maxsum += maxv[n];
#pragma unroll
    for (int k = 0; k < KCL; ++k) {
      float sv = sr[k];
      T1 += sv * rsum[1 + k];
      v[k] += deg * sv;
    }
  }
#pragma unroll
  for (int k = 0; k < KCL; ++k)
    for (int o = 32; o; o >>= 1) v[k] += __shfl_down(v[k], o);
  __shared__ float vpart[16][KCL];
  __shared__ float vfin[KCL];
  if ((t & 63) == 0)
    for (int k = 0; k < KCL; ++k) vpart[t >> 6][k] = v[k];
  float sumDeg_t = block_sum_1024(sumDeg);
  float T1_t = block_sum_1024(T1);
  float maxsum_t = block_sum_1024(maxsum);
  __syncthreads();
  if (t < KCL) {
    float a = 0.f;
    for (int wv = 0; wv < 16; ++wv) a += vpart[wv][t];
    vfin[t] = a;
  }
  __syncthreads();
  float val = (t < 729) ? StS[t] : 0.f;
  float F2 = block_sum_1024(val * val);
  float F = sqrtf(F2);
  bool diag = (t < 729) && (t % 28 == 0);
  float g = (t < 729) ? (val / F - (diag ? (1.f / sqrtf(27.f)) : 0.f)) : 0.f;
  float O2 = block_sum_1024(g * g);
  float ortho = sqrtf(O2);
  if (t == 0) {
    float norm = 0.5f * sumDeg_t;
    float vv = 0.f;
    for (int k = 0; k < KCL; ++k) vv += vfin[k] * vfin[k];
    float c = 0.05f / (2.f * norm);
    float sm = -(T1_t - c * vv) / (2.f * norm);
    float cl = -maxsum_t / (float)NTOT;
    out[0] = sm + cl + ortho;
    out[1] = sm;
  }
}

extern "C" void kernel_launch(void* const* d_in, const int* in_sizes, int n_in,
                              void* d_out, int out_size, void* d_ws, size_t ws_size,
                              hipStream_t stream) {
  const float* x        = (const float*)d_in[0];
  const float* clusters = (const float*)d_in[1];
  const float* alpha    = (const float*)d_in[2];
  float* out = (float*)d_out;
  float* ws  = (float*)d_ws;

  // workspace layout (float offsets)
  const size_t OFF_MERGED = 0;                                  // 8192*512 f32
  const size_t OFF_MBF  = (size_t)NTOT * CDIM;                  // 8192*512 bf16
  const size_t OFF_NCL  = OFF_MBF + (size_t)NTOT * CDIM / 2;
  const size_t OFF_S    = OFF_NCL + (size_t)KCL * CDIM;
  const size_t OFF_ST   = OFF_S + (size_t)NTOT * KCL;           // f32 sT [27][8192]
  const size_t OFF_SXB  = OFF_ST + (size_t)NTOT * KCL;          // bf16 sxT [32][8192]
  const size_t OFF_MAXV = OFF_SXB + (size_t)32 * NTOT / 2;
  const size_t OFF_R    = OFF_MAXV + NTOT;                      // Rpart: 8*8192*28 f32
  const size_t OFF_STS  = OFF_R + (size_t)8 * NTOT * 28;

  unsigned short* mbf  = (unsigned short*)(ws + OFF_MBF);
  unsigned short* sxbf = (unsigned short*)(ws + OFF_SXB);

  hipMemsetAsync(sxbf, 0, (size_t)32 * NTOT * sizeof(unsigned short), stream);
  k_norm_clusters<<<27, 64, 0, stream>>>(clusters, ws + OFF_NCL);
  k_merged<<<128, 256, 0, stream>>>(x, ws + OFF_MERGED, mbf);
  k_inner<<<1024, 256, 0, stream>>>(ws + OFF_MERGED, ws + OFF_NCL, alpha,
                                    ws + OFF_S, ws + OFF_ST, ws + OFF_MAXV,
                                    out + 2, sxbf);
  k_fused<<<dim3(64, 8), 256, 0, stream>>>(mbf, sxbf, ws + OFF_R);
  k_sts<<<729, 256, 0, stream>>>(ws + OFF_ST, ws + OFF_STS);
  k_final<<<1, 1024, 0, stream>>>(ws + OFF_R, ws + OFF_S, ws + OFF_MAXV,
                                  ws + OFF_STS, out);
}

// Round 4
// 251.563 us; speedup vs baseline: 8.8753x; 1.9647x over previous
//
#include <hip/hip_runtime.h>

#define NTOT 8192
#define CDIM 512
#define KCL 27

typedef __attribute__((ext_vector_type(8))) short short8;
typedef __attribute__((ext_vector_type(4))) float f32x4;

static __device__ __forceinline__ unsigned short f2bf(float v) {
  union { float f; unsigned u; } z; z.f = v;
  unsigned r = (z.u + 0x7FFFu + ((z.u >> 16) & 1u)) >> 16;
  return (unsigned short)r;
}

// ---------------- K1: normalize clusters (27 x 512) ----------------
__global__ void k_norm_clusters(const float* __restrict__ cl, float* __restrict__ ncl) {
  int k = blockIdx.x;
  int t = threadIdx.x; // 64
  const float* row = cl + (size_t)k * CDIM;
  float ss = 0.f;
  for (int c = t; c < CDIM; c += 64) { float v = row[c]; ss += v * v; }
  for (int o = 32; o; o >>= 1) ss += __shfl_down(ss, o);
  ss = __shfl(ss, 0);
  float inv = 1.f / fmaxf(sqrtf(ss), 1e-12f);
  for (int c = t; c < CDIM; c += 64) ncl[(size_t)k * CDIM + c] = row[c] * inv;
}

// ---------------- K2: per-pixel L2 norm + permute(0,3,2,1) -> merged[N][C] (f32 + bf16) ----------------
__global__ __launch_bounds__(256) void k_merged(const float* __restrict__ x,
    float* __restrict__ merged, unsigned short* __restrict__ mbf) {
  __shared__ float inv[64];
  __shared__ float part[4][64];
  __shared__ float tile[64][65];
  int bh = blockIdx.x;           // b*64 + h
  int b = bh >> 6, h = bh & 63;
  int t = threadIdx.x;
  int w = t & 63, cg = t >> 6;
  const float* xb = x + (size_t)b * CDIM * 4096 + (size_t)h * 64; // xb[c*4096 + w]
  float ss = 0.f;
  for (int c = cg; c < CDIM; c += 4) {
    float v = xb[(size_t)c * 4096 + w];
    ss += v * v;
  }
  part[cg][w] = ss;
  __syncthreads();
  if (t < 64) {
    float s2 = part[0][t] + part[1][t] + part[2][t] + part[3][t];
    inv[t] = 1.f / fmaxf(sqrtf(s2), 1e-12f);
  }
  __syncthreads();
  for (int c0 = 0; c0 < CDIM; c0 += 64) {
#pragma unroll
    for (int q = 0; q < 16; ++q) {
      int c = cg + q * 4;
      tile[c][w] = xb[(size_t)(c0 + c) * 4096 + w];
    }
    __syncthreads();
#pragma unroll
    for (int q = 0; q < 16; ++q) {
      int ww = cg + q * 4;
      int n = b * 4096 + ww * 64 + h;          // n from permute(0,3,2,1)
      float v = tile[w][ww] * inv[ww];
      merged[(size_t)n * CDIM + c0 + w] = v;
      mbf[(size_t)n * CDIM + c0 + w] = f2bf(v);
    }
    __syncthreads();
  }
}

// ---------------- K3: inner vs clusters, softmax, log_softmax out, max, s, sT, sxT(bf16) ----------------
__global__ __launch_bounds__(256) void k_inner(const float* __restrict__ merged,
    const float* __restrict__ ncl, const float* __restrict__ alpha_p,
    float* __restrict__ s, float* __restrict__ sT, float* __restrict__ maxv,
    float* __restrict__ out_cp, unsigned short* __restrict__ sxbf) {
  __shared__ float ncll[KCL * 513];
  __shared__ float row[CDIM];
  __shared__ float partial[32][8];
  __shared__ float innerl[KCL];
  __shared__ float exps[KCL];
  int t = threadIdx.x;
  float alpha = alpha_p[0];
  for (int idx = t; idx < KCL * CDIM; idx += 256) {
    int k = idx >> 9, c = idx & 511;
    ncll[k * 513 + c] = ncl[idx];
  }
  int k = t & 31, cg = t >> 5;
  for (int r = 0; r < 8; ++r) {
    int n = blockIdx.x * 8 + r;
    __syncthreads();
    for (int c = t; c < CDIM; c += 256) row[c] = merged[(size_t)n * CDIM + c];
    __syncthreads();
    float p = 0.f;
    if (k < KCL) {
      const float* nr = &ncll[k * 513 + cg * 64];
      const float* rr = &row[cg * 64];
#pragma unroll
      for (int i = 0; i < 64; ++i) p += rr[i] * nr[i];
    }
    partial[k][cg] = p;
    __syncthreads();
    if (t < KCL) {
      float v = 0.f;
#pragma unroll
      for (int g = 0; g < 8; ++g) v += partial[t][g];
      innerl[t] = v;
    }
    __syncthreads();
    float mi = 0.f, ml = 0.f, myl = 0.f;
    if (t < KCL) {
      mi = -3.4e38f; ml = -3.4e38f;
      for (int k2 = 0; k2 < KCL; ++k2) {
        float iv = innerl[k2];
        mi = fmaxf(mi, iv);
        ml = fmaxf(ml, iv * alpha);
      }
      myl = innerl[t] * alpha;
      exps[t] = expf(myl - ml);
    }
    __syncthreads();
    if (t < KCL) {
      float sum = 0.f;
      for (int k2 = 0; k2 < KCL; ++k2) sum += exps[k2];
      float sv = exps[t] / sum;
      s[(size_t)n * KCL + t] = sv;
      sT[(size_t)t * NTOT + n] = sv;
      sxbf[(size_t)(t + 1) * NTOT + n] = f2bf(sv);   // Sx rows 1..27
      int b = n >> 12, w = (n >> 6) & 63, h = n & 63;
      out_cp[(((size_t)b * KCL + t) * 64 + h) * 64 + w] = myl - (ml + logf(sum));
      if (t == 0) { maxv[n] = mi; sxbf[n] = 0x3F80; } // Sx row 0 = 1.0
    }
  }
}

// ---------------- K4 (fused): Rpart[jc][28][N] = relu(Mi Mj^T, diag=0) @ [1|S] ----------------
__global__ __launch_bounds__(256) void k_fused(const unsigned short* __restrict__ Mb,
    const unsigned short* __restrict__ sxT, float* __restrict__ Rpart) {
  __shared__ char lds[57344];   // LdsJ 8K | LdsI 8K | Prow 32K | Sx 8K
  char* LdsJ = lds;
  char* LdsI = lds + 8192;
  char* Prow = lds + 16384;
  char* Sx   = lds + 49152;
  int t = threadIdx.x;
  int wid = t >> 6, lane = t & 63;
  int r15 = lane & 15, kgrp = lane >> 4;
  int wrj = wid >> 1, wci = wid & 1;    // j-quadrant / i-quadrant for P-MFMA
  int I0 = blockIdx.x * 128;
  int Jbase = blockIdx.y * 1024;

  f32x4 pv[2][2];
#pragma unroll
  for (int m = 0; m < 2; ++m)
#pragma unroll
    for (int n = 0; n < 2; ++n) pv[m][n] = (f32x4){0.f, 0.f, 0.f, 0.f};

  int srow = wid * 16 + (lane >> 2);
  int scol = (lane & 3) * 8;
  char* lJ0 = LdsJ + wid * 1024;
  char* lJ1 = LdsJ + 4096 + wid * 1024;
  char* lI0 = LdsI + wid * 1024;
  char* lI1 = LdsI + 4096 + wid * 1024;
  const unsigned short* gI0 = Mb + (size_t)(I0 + srow) * CDIM + scol;
  const unsigned short* gI1 = Mb + (size_t)(I0 + 64 + srow) * CDIM + scol;

  for (int jt = 0; jt < 8; ++jt) {
    int J0 = Jbase + jt * 128;
    __syncthreads();   // prev PV readers done before Sx/Prow overwrite

    // stage Sx tile [32 c][128 j] bf16, swizzled byte ^= (c&7)<<4
#pragma unroll
    for (int r2 = 0; r2 < 2; ++r2) {
      int c = r2 * 16 + (t >> 4);
      int jsrc = (t & 15) * 8;
      uint4 d = *(const uint4*)(sxT + (size_t)c * NTOT + J0 + jsrc);
      *(uint4*)(Sx + c * 256 + (((t & 15) * 16) ^ ((c & 7) << 4))) = d;
    }

    f32x4 acc[4][4];
#pragma unroll
    for (int m = 0; m < 4; ++m)
#pragma unroll
      for (int n = 0; n < 4; ++n) acc[m][n] = (f32x4){0.f, 0.f, 0.f, 0.f};

    const unsigned short* gJ0 = Mb + (size_t)(J0 + srow) * CDIM + scol;
    const unsigned short* gJ1 = Mb + (size_t)(J0 + 64 + srow) * CDIM + scol;
    for (int k0 = 0; k0 < CDIM; k0 += 32) {
      __builtin_amdgcn_global_load_lds(
          (const __attribute__((address_space(1))) void*)(gJ0 + k0),
          (__attribute__((address_space(3))) void*)lJ0, 16, 0, 0);
      __builtin_amdgcn_global_load_lds(
          (const __attribute__((address_space(1))) void*)(gJ1 + k0),
          (__attribute__((address_space(3))) void*)lJ1, 16, 0, 0);
      __builtin_amdgcn_global_load_lds(
          (const __attribute__((address_space(1))) void*)(gI0 + k0),
          (__attribute__((address_space(3))) void*)lI0, 16, 0, 0);
      __builtin_amdgcn_global_load_lds(
          (const __attribute__((address_space(1))) void*)(gI1 + k0),
          (__attribute__((address_space(3))) void*)lI1, 16, 0, 0);
      __syncthreads();

      short8 a[4], b[4];
#pragma unroll
      for (int m = 0; m < 4; ++m)
        a[m] = *(const short8*)(LdsJ + ((wrj * 64 + m * 16 + r15) * 64 + kgrp * 16));
#pragma unroll
      for (int n = 0; n < 4; ++n)
        b[n] = *(const short8*)(LdsI + ((wci * 64 + n * 16 + r15) * 64 + kgrp * 16));
#pragma unroll
      for (int m = 0; m < 4; ++m)
#pragma unroll
        for (int n = 0; n < 4; ++n)
          acc[m][n] = __builtin_amdgcn_mfma_f32_16x16x32_bf16(a[m], b[n], acc[m][n], 0, 0, 0);
      __syncthreads();
    }

    // acc = P^T tile: row j = wrj*64+m*16+kgrp*4+reg, col i = wci*64+n*16+r15
#pragma unroll
    for (int m = 0; m < 4; ++m) {
#pragma unroll
      for (int n = 0; n < 4; ++n) {
        int iloc = wci * 64 + n * 16 + r15;
        int gi = I0 + iloc;
        int jloc = wrj * 64 + m * 16 + kgrp * 4;
        int gj = J0 + jloc;
        unsigned short h[4];
#pragma unroll
        for (int reg = 0; reg < 4; ++reg) {
          float v = acc[m][n][reg];
          v = v > 0.f ? v : 0.f;
          if (gj + reg == gi) v = 0.f;
          h[reg] = f2bf(v);
        }
        uint2 pk;
        pk.x = (unsigned)h[0] | ((unsigned)h[1] << 16);
        pk.y = (unsigned)h[2] | ((unsigned)h[3] << 16);
        *(uint2*)(Prow + iloc * 256 + ((jloc * 2) ^ ((iloc & 7) << 4))) = pk;
      }
    }
    __syncthreads();

    // PV: pv += Ptile(128x128) @ Sx(128x32); wave owns rows wid*32..+32
#pragma unroll
    for (int ks = 0; ks < 4; ++ks) {
      short8 a2[2], b2[2];
#pragma unroll
      for (int m2 = 0; m2 < 2; ++m2) {
        int iloc = wid * 32 + m2 * 16 + r15;
        a2[m2] = *(const short8*)(Prow + iloc * 256 +
                                  ((ks * 64 + kgrp * 16) ^ ((iloc & 7) << 4)));
      }
#pragma unroll
      for (int n2 = 0; n2 < 2; ++n2) {
        int c = n2 * 16 + r15;
        b2[n2] = *(const short8*)(Sx + c * 256 +
                                  ((ks * 64 + kgrp * 16) ^ ((c & 7) << 4)));
      }
#pragma unroll
      for (int m2 = 0; m2 < 2; ++m2)
#pragma unroll
        for (int n2 = 0; n2 < 2; ++n2)
          pv[m2][n2] = __builtin_amdgcn_mfma_f32_16x16x32_bf16(a2[m2], b2[n2], pv[m2][n2], 0, 0, 0);
    }
  }

  // write transposed Rpart[jc][c][gi]: 4 consecutive gi per lane -> float4 store
#pragma unroll
  for (int m2 = 0; m2 < 2; ++m2) {
#pragma unroll
    for (int n2 = 0; n2 < 2; ++n2) {
      int c = n2 * 16 + r15;
      if (c < 28) {
        int gi = I0 + wid * 32 + m2 * 16 + kgrp * 4;
        *(f32x4*)(&Rpart[((size_t)blockIdx.y * 28 + c) * NTOT + gi]) = pv[m2][n2];
      }
    }
  }
}

// ---------------- K6: StS[27][27] = S^T S (via sT rows) ----------------
__global__ void k_sts(const float* __restrict__ sT, float* __restrict__ StS) {
  int k = blockIdx.x / KCL, l = blockIdx.x % KCL;
  int t = threadIdx.x; // 256
  const float* a = sT + (size_t)k * NTOT;
  const float* b = sT + (size_t)l * NTOT;
  float acc = 0.f;
  for (int n = t; n < NTOT; n += 256) acc += a[n] * b[n];
  for (int o = 32; o; o >>= 1) acc += __shfl_down(acc, o);
  __shared__ float sc[4];
  if ((t & 63) == 0) sc[t >> 6] = acc;
  __syncthreads();
  if (t == 0) StS[blockIdx.x] = sc[0] + sc[1] + sc[2] + sc[3];
}

// ---------------- K7a: grid-parallel reduction of Rpart -> 32x30 partials ----------------
__global__ __launch_bounds__(256) void k_reduce1(const float* __restrict__ Rpart,
    const float* __restrict__ sT, const float* __restrict__ maxv,
    float* __restrict__ partials) {
  int t = threadIdx.x;
  int n = blockIdx.x * 256 + t;
  float rsum[28];
#pragma unroll
  for (int c = 0; c < 28; ++c) rsum[c] = 0.f;
#pragma unroll
  for (int bs = 0; bs < 8; ++bs)
#pragma unroll
    for (int c = 0; c < 28; ++c)
      rsum[c] += Rpart[((size_t)bs * 28 + c) * NTOT + n];
  float deg = rsum[0];
  float T1 = 0.f;
  float vloc[KCL];
#pragma unroll
  for (int k = 0; k < KCL; ++k) {
    float sv = sT[(size_t)k * NTOT + n];
    T1 += sv * rsum[1 + k];
    vloc[k] = deg * sv;
  }
  float mx = maxv[n];
  for (int o = 32; o; o >>= 1) {
    deg += __shfl_down(deg, o);
    T1 += __shfl_down(T1, o);
    mx += __shfl_down(mx, o);
  }
#pragma unroll
  for (int k = 0; k < KCL; ++k)
    for (int o = 32; o; o >>= 1) vloc[k] += __shfl_down(vloc[k], o);
  __shared__ float red[4][30];
  int wv = t >> 6;
  if ((t & 63) == 0) {
    red[wv][0] = deg; red[wv][1] = T1; red[wv][2] = mx;
#pragma unroll
    for (int k = 0; k < KCL; ++k) red[wv][3 + k] = vloc[k];
  }
  __syncthreads();
  if (t < 30)
    partials[blockIdx.x * 30 + t] = red[0][t] + red[1][t] + red[2][t] + red[3][t];
}

// ---------------- K7b: tiny final combine + ortho ----------------
__device__ float block_sum_1024(float v) {
  __shared__ float sc[16];
  for (int o = 32; o; o >>= 1) v += __shfl_down(v, o);
  __syncthreads();
  if ((threadIdx.x & 63) == 0) sc[threadIdx.x >> 6] = v;
  __syncthreads();
  if (threadIdx.x == 0) {
    float r = 0.f;
    for (int i = 0; i < 16; ++i) r += sc[i];
    sc[0] = r;
  }
  __syncthreads();
  return sc[0];
}

__global__ __launch_bounds__(1024) void k_final2(const float* __restrict__ partials,
    const float* __restrict__ StS, float* __restrict__ out) {
  __shared__ float comb[30];
  int t = threadIdx.x;
  if (t < 30) {
    float a = 0.f;
    for (int b = 0; b < 32; ++b) a += partials[b * 30 + t];
    comb[t] = a;
  }
  __syncthreads();
  float val = (t < 729) ? StS[t] : 0.f;
  float F2 = block_sum_1024(val * val);
  float F = sqrtf(F2);
  bool diag = (t < 729) && (t % 28 == 0);
  float g = (t < 729) ? (val / F - (diag ? (1.f / sqrtf(27.f)) : 0.f)) : 0.f;
  float O2 = block_sum_1024(g * g);
  float ortho = sqrtf(O2);
  if (t == 0) {
    float sumDeg = comb[0], T1 = comb[1], maxsum = comb[2];
    float norm = 0.5f * sumDeg;
    float vv = 0.f;
    for (int k = 0; k < KCL; ++k) vv += comb[3 + k] * comb[3 + k];
    float c = 0.05f / (2.f * norm);
    float sm = -(T1 - c * vv) / (2.f * norm);
    float cl = -maxsum / (float)NTOT;
    out[0] = sm + cl + ortho;
    out[1] = sm;
  }
}

extern "C" void kernel_launch(void* const* d_in, const int* in_sizes, int n_in,
                              void* d_out, int out_size, void* d_ws, size_t ws_size,
                              hipStream_t stream) {
  const float* x        = (const float*)d_in[0];
  const float* clusters = (const float*)d_in[1];
  const float* alpha    = (const float*)d_in[2];
  float* out = (float*)d_out;
  float* ws  = (float*)d_ws;

  // workspace layout (float offsets)
  const size_t OFF_MERGED = 0;                                  // 8192*512 f32
  const size_t OFF_MBF  = (size_t)NTOT * CDIM;                  // 8192*512 bf16
  const size_t OFF_NCL  = OFF_MBF + (size_t)NTOT * CDIM / 2;
  const size_t OFF_S    = OFF_NCL + (size_t)KCL * CDIM;
  const size_t OFF_ST   = OFF_S + (size_t)NTOT * KCL;           // f32 sT [27][8192]
  const size_t OFF_SXB  = OFF_ST + (size_t)NTOT * KCL;          // bf16 sxT [32][8192]
  const size_t OFF_MAXV = OFF_SXB + (size_t)32 * NTOT / 2;
  const size_t OFF_R    = OFF_MAXV + NTOT;                      // Rpart: 8*28*8192 f32
  const size_t OFF_STS  = OFF_R + (size_t)8 * 28 * NTOT;
  const size_t OFF_PART = OFF_STS + 768;                        // 32*30 partials

  unsigned short* mbf  = (unsigned short*)(ws + OFF_MBF);
  unsigned short* sxbf = (unsigned short*)(ws + OFF_SXB);

  hipMemsetAsync(sxbf, 0, (size_t)32 * NTOT * sizeof(unsigned short), stream);
  k_norm_clusters<<<27, 64, 0, stream>>>(clusters, ws + OFF_NCL);
  k_merged<<<128, 256, 0, stream>>>(x, ws + OFF_MERGED, mbf);
  k_inner<<<1024, 256, 0, stream>>>(ws + OFF_MERGED, ws + OFF_NCL, alpha,
                                    ws + OFF_S, ws + OFF_ST, ws + OFF_MAXV,
                                    out + 2, sxbf);
  k_fused<<<dim3(64, 8), 256, 0, stream>>>(mbf, sxbf, ws + OFF_R);
  k_sts<<<729, 256, 0, stream>>>(ws + OFF_ST, ws + OFF_STS);
  k_reduce1<<<32, 256, 0, stream>>>(ws + OFF_R, ws + OFF_ST, ws + OFF_MAXV,
                                    ws + OFF_PART);
  k_final2<<<1, 1024, 0, stream>>>(ws + OFF_PART, ws + OFF_STS, out);
}

// Round 5
// 235.481 us; speedup vs baseline: 9.4814x; 1.0683x over previous
//
#include <hip/hip_runtime.h>

#define NTOT 8192
#define CDIM 512
#define KCL 27

typedef __attribute__((ext_vector_type(8))) short short8;
typedef __attribute__((ext_vector_type(4))) float f32x4;

static __device__ __forceinline__ unsigned short f2bf(float v) {
  union { float f; unsigned u; } z; z.f = v;
  unsigned r = (z.u + 0x7FFFu + ((z.u >> 16) & 1u)) >> 16;
  return (unsigned short)r;
}

// ---------------- K1: normalize clusters -> nclb bf16 [32][512] (rows 27..31 pre-zeroed) ----------------
__global__ void k_norm_clusters(const float* __restrict__ cl, unsigned short* __restrict__ nclb) {
  int k = blockIdx.x;
  int t = threadIdx.x; // 64
  const float* row = cl + (size_t)k * CDIM;
  float ss = 0.f;
  for (int c = t; c < CDIM; c += 64) { float v = row[c]; ss += v * v; }
  for (int o = 32; o; o >>= 1) ss += __shfl_down(ss, o);
  ss = __shfl(ss, 0);
  float inv = 1.f / fmaxf(sqrtf(ss), 1e-12f);
  for (int c = t; c < CDIM; c += 64) nclb[(size_t)k * CDIM + c] = f2bf(row[c] * inv);
}

// ---------------- K2: per-pixel L2 norm + permute(0,3,2,1) -> mbf bf16 [N][C] ----------------
__global__ __launch_bounds__(256) void k_merged(const float* __restrict__ x,
    unsigned short* __restrict__ mbf) {
  __shared__ float inv[64];
  __shared__ float part[4][64];
  __shared__ float tile[64][65];
  int bh = blockIdx.x;           // b*64 + h
  int b = bh >> 6, h = bh & 63;
  int t = threadIdx.x;
  int w = t & 63, cg = t >> 6;
  const float* xb = x + (size_t)b * CDIM * 4096 + (size_t)h * 64; // xb[c*4096 + w]
  float ss = 0.f;
  for (int c = cg; c < CDIM; c += 4) {
    float v = xb[(size_t)c * 4096 + w];
    ss += v * v;
  }
  part[cg][w] = ss;
  __syncthreads();
  if (t < 64) {
    float s2 = part[0][t] + part[1][t] + part[2][t] + part[3][t];
    inv[t] = 1.f / fmaxf(sqrtf(s2), 1e-12f);
  }
  __syncthreads();
  for (int c0 = 0; c0 < CDIM; c0 += 64) {
#pragma unroll
    for (int q = 0; q < 16; ++q) {
      int c = cg + q * 4;
      tile[c][w] = xb[(size_t)(c0 + c) * 4096 + w];
    }
    __syncthreads();
#pragma unroll
    for (int q = 0; q < 16; ++q) {
      int ww = cg + q * 4;
      int n = b * 4096 + ww * 64 + h;          // n from permute(0,3,2,1)
      mbf[(size_t)n * CDIM + c0 + w] = f2bf(tile[w][ww] * inv[ww]);
    }
    __syncthreads();
  }
}

// ---------------- K3 (MFMA): inner = mbf @ nclb^T; softmax/log_softmax/max; sT, sxbf, out_cp, maxv ----------------
// 256 blocks x 32 rows. 4 waves split K (each 128); LDS combine; parallel epilogue.
__global__ __launch_bounds__(256) void k_inner2(const unsigned short* __restrict__ mbf,
    const unsigned short* __restrict__ nclb, const float* __restrict__ alpha_p,
    float* __restrict__ sT, float* __restrict__ maxv,
    float* __restrict__ out_cp, unsigned short* __restrict__ sxbf) {
  __shared__ float red[4][32][33];
  __shared__ float innerS[32][33];
  __shared__ float rowml[32], rowls[32], rowinv[32];
  int t = threadIdx.x;
  int wv = t >> 6, lane = t & 63;
  int r15 = lane & 15, kgrp = lane >> 4;
  int I0 = blockIdx.x * 32;
  float alpha = alpha_p[0];

  f32x4 acc[2][2];
#pragma unroll
  for (int m = 0; m < 2; ++m)
#pragma unroll
    for (int n = 0; n < 2; ++n) acc[m][n] = (f32x4){0.f, 0.f, 0.f, 0.f};

#pragma unroll
  for (int ks = 0; ks < 4; ++ks) {
    int kbase = wv * 128 + ks * 32 + kgrp * 8;
    short8 a[2], b[2];
#pragma unroll
    for (int m = 0; m < 2; ++m)
      a[m] = *(const short8*)(mbf + (size_t)(I0 + m * 16 + r15) * CDIM + kbase);
#pragma unroll
    for (int n = 0; n < 2; ++n)
      b[n] = *(const short8*)(nclb + (size_t)(n * 16 + r15) * CDIM + kbase);
#pragma unroll
    for (int m = 0; m < 2; ++m)
#pragma unroll
      for (int n = 0; n < 2; ++n)
        acc[m][n] = __builtin_amdgcn_mfma_f32_16x16x32_bf16(a[m], b[n], acc[m][n], 0, 0, 0);
  }
  // C/D layout: col = lane&15, row = kgrp*4 + reg
#pragma unroll
  for (int m = 0; m < 2; ++m)
#pragma unroll
    for (int n = 0; n < 2; ++n)
#pragma unroll
      for (int reg = 0; reg < 4; ++reg)
        red[wv][m * 16 + kgrp * 4 + reg][n * 16 + r15] = acc[m][n][reg];
  __syncthreads();
  for (int idx = t; idx < 1024; idx += 256) {
    int r = idx >> 5, c = idx & 31;
    innerS[r][c] = red[0][r][c] + red[1][r][c] + red[2][r][c] + red[3][r][c];
  }
  __syncthreads();
  if (t < 32) {
    float mi = -3.4e38f, ml = -3.4e38f;
    for (int k = 0; k < KCL; ++k) {
      float iv = innerS[t][k];
      mi = fmaxf(mi, iv);
      ml = fmaxf(ml, alpha * iv);
    }
    float sum = 0.f;
    for (int k = 0; k < KCL; ++k) sum += expf(alpha * innerS[t][k] - ml);
    rowml[t] = ml;
    rowls[t] = ml + logf(sum);
    rowinv[t] = 1.f / sum;
    maxv[I0 + t] = mi;
    sxbf[I0 + t] = 0x3F80;                     // Sx row 0 = 1.0
  }
  __syncthreads();
  for (int idx = t; idx < 32 * KCL; idx += 256) {
    int r = idx / KCL, k = idx - r * KCL;
    int n = I0 + r;
    float iv = innerS[r][k];
    float sv = expf(alpha * iv - rowml[r]) * rowinv[r];
    sT[(size_t)k * NTOT + n] = sv;
    sxbf[(size_t)(k + 1) * NTOT + n] = f2bf(sv);
    int b = n >> 12, w = (n >> 6) & 63, h = n & 63;
    out_cp[(((size_t)b * KCL + k) * 64 + h) * 64 + w] = alpha * iv - rowls[r];
  }
}

// ---------------- K4 (fused): Rpart[jc][28][N] = relu(Mi Mj^T, diag=0) @ [1|S] ----------------
__global__ __launch_bounds__(256) void k_fused(const unsigned short* __restrict__ Mb,
    const unsigned short* __restrict__ sxT, float* __restrict__ Rpart) {
  __shared__ char lds[49152];   // LdsJ 8K | LdsI 8K | Prow 32K
  char* LdsJ = lds;
  char* LdsI = lds + 8192;
  char* Prow = lds + 16384;
  int t = threadIdx.x;
  int wid = t >> 6, lane = t & 63;
  int r15 = lane & 15, kgrp = lane >> 4;
  int wrj = wid >> 1, wci = wid & 1;    // j-quadrant / i-quadrant for P-MFMA
  int I0 = blockIdx.x * 128;
  int Jbase = blockIdx.y * 1024;

  f32x4 pv[2][2];
#pragma unroll
  for (int m = 0; m < 2; ++m)
#pragma unroll
    for (int n = 0; n < 2; ++n) pv[m][n] = (f32x4){0.f, 0.f, 0.f, 0.f};

  int srow = wid * 16 + (lane >> 2);
  int scol = (lane & 3) * 8;
  char* lJ0 = LdsJ + wid * 1024;
  char* lJ1 = LdsJ + 4096 + wid * 1024;
  char* lI0 = LdsI + wid * 1024;
  char* lI1 = LdsI + 4096 + wid * 1024;
  const unsigned short* gI0 = Mb + (size_t)(I0 + srow) * CDIM + scol;
  const unsigned short* gI1 = Mb + (size_t)(I0 + 64 + srow) * CDIM + scol;

  for (int jt = 0; jt < 8; ++jt) {
    int J0 = Jbase + jt * 128;

    f32x4 acc[4][4];
#pragma unroll
    for (int m = 0; m < 4; ++m)
#pragma unroll
      for (int n = 0; n < 4; ++n) acc[m][n] = (f32x4){0.f, 0.f, 0.f, 0.f};

    const unsigned short* gJ0 = Mb + (size_t)(J0 + srow) * CDIM + scol;
    const unsigned short* gJ1 = Mb + (size_t)(J0 + 64 + srow) * CDIM + scol;
    for (int k0 = 0; k0 < CDIM; k0 += 32) {
      __builtin_amdgcn_global_load_lds(
          (const __attribute__((address_space(1))) void*)(gJ0 + k0),
          (__attribute__((address_space(3))) void*)lJ0, 16, 0, 0);
      __builtin_amdgcn_global_load_lds(
          (const __attribute__((address_space(1))) void*)(gJ1 + k0),
          (__attribute__((address_space(3))) void*)lJ1, 16, 0, 0);
      __builtin_amdgcn_global_load_lds(
          (const __attribute__((address_space(1))) void*)(gI0 + k0),
          (__attribute__((address_space(3))) void*)lI0, 16, 0, 0);
      __builtin_amdgcn_global_load_lds(
          (const __attribute__((address_space(1))) void*)(gI1 + k0),
          (__attribute__((address_space(3))) void*)lI1, 16, 0, 0);
      __syncthreads();   // drains vmcnt: staged data visible

      short8 a[4], b[4];
#pragma unroll
      for (int m = 0; m < 4; ++m)
        a[m] = *(const short8*)(LdsJ + ((wrj * 64 + m * 16 + r15) * 64 + kgrp * 16));
#pragma unroll
      for (int n = 0; n < 4; ++n)
        b[n] = *(const short8*)(LdsI + ((wci * 64 + n * 16 + r15) * 64 + kgrp * 16));
#pragma unroll
      for (int m = 0; m < 4; ++m)
#pragma unroll
        for (int n = 0; n < 4; ++n)
          acc[m][n] = __builtin_amdgcn_mfma_f32_16x16x32_bf16(a[m], b[n], acc[m][n], 0, 0, 0);
      __syncthreads();
    }

    // acc = P^T tile: row j = wrj*64+m*16+kgrp*4+reg, col i = wci*64+n*16+r15
#pragma unroll
    for (int m = 0; m < 4; ++m) {
#pragma unroll
      for (int n = 0; n < 4; ++n) {
        int iloc = wci * 64 + n * 16 + r15;
        int gi = I0 + iloc;
        int jloc = wrj * 64 + m * 16 + kgrp * 4;
        int gj = J0 + jloc;
        unsigned short h[4];
#pragma unroll
        for (int reg = 0; reg < 4; ++reg) {
          float v = acc[m][n][reg];
          v = v > 0.f ? v : 0.f;
          if (gj + reg == gi) v = 0.f;
          h[reg] = f2bf(v);
        }
        uint2 pk;
        pk.x = (unsigned)h[0] | ((unsigned)h[1] << 16);
        pk.y = (unsigned)h[2] | ((unsigned)h[3] << 16);
        *(uint2*)(Prow + iloc * 256 + ((jloc * 2) ^ ((iloc & 7) << 4))) = pk;
      }
    }
    __syncthreads();

    // PV: pv += Ptile(128x128) @ SxT-frags (direct from L2-resident global)
#pragma unroll
    for (int ks = 0; ks < 4; ++ks) {
      short8 a2[2], b2[2];
#pragma unroll
      for (int m2 = 0; m2 < 2; ++m2) {
        int iloc = wid * 32 + m2 * 16 + r15;
        a2[m2] = *(const short8*)(Prow + iloc * 256 +
                                  ((ks * 64 + kgrp * 16) ^ ((iloc & 7) << 4)));
      }
#pragma unroll
      for (int n2 = 0; n2 < 2; ++n2) {
        int c = n2 * 16 + r15;
        b2[n2] = *(const short8*)(sxT + (size_t)c * NTOT + J0 + ks * 32 + kgrp * 8);
      }
#pragma unroll
      for (int m2 = 0; m2 < 2; ++m2)
#pragma unroll
        for (int n2 = 0; n2 < 2; ++n2)
          pv[m2][n2] = __builtin_amdgcn_mfma_f32_16x16x32_bf16(a2[m2], b2[n2], pv[m2][n2], 0, 0, 0);
    }
  }

  // write transposed Rpart[jc][c][gi]: 4 consecutive gi per lane -> float4 store
#pragma unroll
  for (int m2 = 0; m2 < 2; ++m2) {
#pragma unroll
    for (int n2 = 0; n2 < 2; ++n2) {
      int c = n2 * 16 + r15;
      if (c < 28) {
        int gi = I0 + wid * 32 + m2 * 16 + kgrp * 4;
        *(f32x4*)(&Rpart[((size_t)blockIdx.y * 28 + c) * NTOT + gi]) = pv[m2][n2];
      }
    }
  }
}

// ---------------- K6: StS[27][27] = S^T S (via sT rows) ----------------
__global__ void k_sts(const float* __restrict__ sT, float* __restrict__ StS) {
  int k = blockIdx.x / KCL, l = blockIdx.x % KCL;
  int t = threadIdx.x; // 256
  const float* a = sT + (size_t)k * NTOT;
  const float* b = sT + (size_t)l * NTOT;
  float acc = 0.f;
  for (int n = t; n < NTOT; n += 256) acc += a[n] * b[n];
  for (int o = 32; o; o >>= 1) acc += __shfl_down(acc, o);
  __shared__ float sc[4];
  if ((t & 63) == 0) sc[t >> 6] = acc;
  __syncthreads();
  if (t == 0) StS[blockIdx.x] = sc[0] + sc[1] + sc[2] + sc[3];
}

// ---------------- K7a: grid-parallel reduction of Rpart -> 32x30 partials ----------------
__global__ __launch_bounds__(256) void k_reduce1(const float* __restrict__ Rpart,
    const float* __restrict__ sT, const float* __restrict__ maxv,
    float* __restrict__ partials) {
  int t = threadIdx.x;
  int n = blockIdx.x * 256 + t;
  float rsum[28];
#pragma unroll
  for (int c = 0; c < 28; ++c) rsum[c] = 0.f;
#pragma unroll
  for (int bs = 0; bs < 8; ++bs)
#pragma unroll
    for (int c = 0; c < 28; ++c)
      rsum[c] += Rpart[((size_t)bs * 28 + c) * NTOT + n];
  float deg = rsum[0];
  float T1 = 0.f;
  float vloc[KCL];
#pragma unroll
  for (int k = 0; k < KCL; ++k) {
    float sv = sT[(size_t)k * NTOT + n];
    T1 += sv * rsum[1 + k];
    vloc[k] = deg * sv;
  }
  float mx = maxv[n];
  for (int o = 32; o; o >>= 1) {
    deg += __shfl_down(deg, o);
    T1 += __shfl_down(T1, o);
    mx += __shfl_down(mx, o);
  }
#pragma unroll
  for (int k = 0; k < KCL; ++k)
    for (int o = 32; o; o >>= 1) vloc[k] += __shfl_down(vloc[k], o);
  __shared__ float red[4][30];
  int wv = t >> 6;
  if ((t & 63) == 0) {
    red[wv][0] = deg; red[wv][1] = T1; red[wv][2] = mx;
#pragma unroll
    for (int k = 0; k < KCL; ++k) red[wv][3 + k] = vloc[k];
  }
  __syncthreads();
  if (t < 30)
    partials[blockIdx.x * 30 + t] = red[0][t] + red[1][t] + red[2][t] + red[3][t];
}

// ---------------- K7b: tiny final combine + ortho ----------------
__device__ float block_sum_1024(float v) {
  __shared__ float sc[16];
  for (int o = 32; o; o >>= 1) v += __shfl_down(v, o);
  __syncthreads();
  if ((threadIdx.x & 63) == 0) sc[threadIdx.x >> 6] = v;
  __syncthreads();
  if (threadIdx.x == 0) {
    float r = 0.f;
    for (int i = 0; i < 16; ++i) r += sc[i];
    sc[0] = r;
  }
  __syncthreads();
  return sc[0];
}

__global__ __launch_bounds__(1024) void k_final2(const float* __restrict__ partials,
    const float* __restrict__ StS, float* __restrict__ out) {
  __shared__ float comb[30];
  int t = threadIdx.x;
  if (t < 30) {
    float a = 0.f;
    for (int b = 0; b < 32; ++b) a += partials[b * 30 + t];
    comb[t] = a;
  }
  __syncthreads();
  float val = (t < 729) ? StS[t] : 0.f;
  float F2 = block_sum_1024(val * val);
  float F = sqrtf(F2);
  bool diag = (t < 729) && (t % 28 == 0);
  float g = (t < 729) ? (val / F - (diag ? (1.f / sqrtf(27.f)) : 0.f)) : 0.f;
  float O2 = block_sum_1024(g * g);
  float ortho = sqrtf(O2);
  if (t == 0) {
    float sumDeg = comb[0], T1 = comb[1], maxsum = comb[2];
    float norm = 0.5f * sumDeg;
    float vv = 0.f;
    for (int k = 0; k < KCL; ++k) vv += comb[3 + k] * comb[3 + k];
    float c = 0.05f / (2.f * norm);
    float sm = -(T1 - c * vv) / (2.f * norm);
    float cl = -maxsum / (float)NTOT;
    out[0] = sm + cl + ortho;
    out[1] = sm;
  }
}

extern "C" void kernel_launch(void* const* d_in, const int* in_sizes, int n_in,
                              void* d_out, int out_size, void* d_ws, size_t ws_size,
                              hipStream_t stream) {
  const float* x        = (const float*)d_in[0];
  const float* clusters = (const float*)d_in[1];
  const float* alpha    = (const float*)d_in[2];
  float* out = (float*)d_out;
  float* ws  = (float*)d_ws;

  // workspace layout (float offsets)
  const size_t OFF_MBF  = 0;                                    // bf16 [8192][512]
  const size_t OFF_NCLB = (size_t)NTOT * CDIM / 2;              // bf16 [32][512]
  const size_t OFF_ST   = OFF_NCLB + (size_t)32 * CDIM / 2;     // f32 sT [27][8192]
  const size_t OFF_SXB  = OFF_ST + (size_t)NTOT * KCL;          // bf16 sxT [32][8192]
  const size_t OFF_MAXV = OFF_SXB + (size_t)32 * NTOT / 2;
  const size_t OFF_R    = OFF_MAXV + NTOT;                      // Rpart: 8*28*8192 f32
  const size_t OFF_STS  = OFF_R + (size_t)8 * 28 * NTOT;
  const size_t OFF_PART = OFF_STS + 768;                        // 32*30 partials

  unsigned short* mbf  = (unsigned short*)(ws + OFF_MBF);
  unsigned short* nclb = (unsigned short*)(ws + OFF_NCLB);
  unsigned short* sxbf = (unsigned short*)(ws + OFF_SXB);

  hipMemsetAsync(sxbf, 0, (size_t)32 * NTOT * sizeof(unsigned short), stream);
  hipMemsetAsync(nclb, 0, (size_t)32 * CDIM * sizeof(unsigned short), stream);
  k_norm_clusters<<<27, 64, 0, stream>>>(clusters, nclb);
  k_merged<<<128, 256, 0, stream>>>(x, mbf);
  k_inner2<<<256, 256, 0, stream>>>(mbf, nclb, alpha,
                                    ws + OFF_ST, ws + OFF_MAXV, out + 2, sxbf);
  k_fused<<<dim3(64, 8), 256, 0, stream>>>(mbf, sxbf, ws + OFF_R);
  k_sts<<<729, 256, 0, stream>>>(ws + OFF_ST, ws + OFF_STS);
  k_reduce1<<<32, 256, 0, stream>>>(ws + OFF_R, ws + OFF_ST, ws + OFF_MAXV,
                                    ws + OFF_PART);
  k_final2<<<1, 1024, 0, stream>>>(ws + OFF_PART, ws + OFF_STS, out);
}